// Round 1
// 793.698 us; speedup vs baseline: 1.0611x; 1.0611x over previous
//
#include <hip/hip_runtime.h>

constexpr int G = 64;
constexpr int C = 16;
constexpr int NBATCH = 4;
constexpr int HID = 96;
constexpr int G3 = G * G * G; // 262144 = 2^18

// ---------------------------------------------------------------------------
// Pass 1: perception (edge-padded sobel stencil) + fused MLP + stochastic
// update. Key change vs previous version: the 96-wide hidden vector is never
// materialized. We hold the 64 perception features p[64] in registers and
// stream over hidden units y, folding relu(b1[y] + w1[y,:]·p) straight into
// delta[0..15] via w2[:,y]. Live regs ~= p[64]+delta[16]+temps ≈ 100 VGPR
// (previous hid[96] version spilled past its 76 VGPRs -> 25% occupancy).
// One 8x8x8 voxel tile per block, 512 threads, 1 voxel/thread.
// ---------------------------------------------------------------------------
__global__ __launch_bounds__(512)
void nca_update(const float* __restrict__ state, const float* __restrict__ rand_u,
                const float* __restrict__ w1, const float* __restrict__ b1,
                const float* __restrict__ w2,
                float* __restrict__ out, float* __restrict__ premask)
{
    __shared__ float tile[C][10][10][10]; // 64000 B -> 2 blocks/CU

    const int tid = threadIdx.x;
    const int bid = blockIdx.x;
    const int bx = bid & 7, by = (bid >> 3) & 7, bz = (bid >> 6) & 7, n = bid >> 9;
    const int x0 = bx * 8, y0 = by * 8, z0 = bz * 8;
    const float* sb = state + (size_t)n * C * G3;

    // Cooperative load of 10^3 halo tile x 16 channels, edge-clamped.
    for (int i = tid; i < C * 1000; i += 512) {
        int lx = i % 10;
        int t = i / 10;
        int ly = t % 10; t /= 10;
        int lz = t % 10;
        int c  = t / 10;
        int gx = min(max(x0 + lx - 1, 0), G - 1);
        int gy = min(max(y0 + ly - 1, 0), G - 1);
        int gz = min(max(z0 + lz - 1, 0), G - 1);
        tile[c][lz][ly][lx] = sb[(size_t)c * G3 + (size_t)gz * (G * G) + gy * G + gx];
    }
    __syncthreads();

    const int lx = (tid & 7) + 1, ly = ((tid >> 3) & 7) + 1, lz = (tid >> 6) + 1;

    // Perception features, layout matches w1 columns: x = k*16 + c
    // (k: 0=identity, 1=sobel-z, 2=sobel-y, 3=sobel-x).
    float p[64];
    float amax = -3.0e38f; // 3^3 max of old alpha (c==3); clamped-edge == SAME pool

#pragma unroll
    for (int c = 0; c < C; ++c) {
        // Plane sums: P (g over y,x; s over z), U (g over z,x; s over y),
        //             V (g over z,y; s over x).
        float P0 = 0.f, P2 = 0.f, U0 = 0.f, U2 = 0.f, V0 = 0.f, V2 = 0.f;
        float ctr = 0.f, mx = -3.0e38f;
#pragma unroll
        for (int dz = 0; dz < 3; ++dz) {
            const float gz = (dz == 1) ? 2.f : 1.f;
#pragma unroll
            for (int dy = 0; dy < 3; ++dy) {
                const float gy = (dy == 1) ? 2.f : 1.f;
                const float* r = &tile[c][lz + dz - 1][ly + dy - 1][lx - 1];
                const float a0 = r[0], a1 = r[1], a2 = r[2];
                const float rs = a0 + 2.f * a1 + a2; // g over x
                if (dz == 0) P0 += gy * rs;
                if (dz == 2) P2 += gy * rs;
                if (dy == 0) U0 += gz * rs;
                if (dy == 2) U2 += gz * rs;
                V0 += gz * gy * a0;
                V2 += gz * gy * a2;
                if (dz == 1 && dy == 1) ctr = a1;
                if (c == 3) mx = fmaxf(mx, fmaxf(fmaxf(a0, a1), a2));
            }
        }
        if (c == 3) amax = mx;

        p[c]      = ctr;                    // identity
        p[16 + c] = (P0 - P2) * 0.0625f;    // sobel along d(z)
        p[32 + c] = (U0 - U2) * 0.0625f;    // sobel along h(y)
        p[48 + c] = (V0 - V2) * 0.0625f;    // sobel along w(x)
    }

    float delta[C];
#pragma unroll
    for (int c = 0; c < C; ++c) delta[c] = 0.f;

    // Fused MLP: stream hidden units; h never lives past one iteration.
    // w1 rows are contiguous (256 B) -> s_load_dwordx16 batches; all weight
    // reads are wave-uniform scalar loads.
#pragma unroll 2
    for (int y = 0; y < HID; ++y) {
        const float* wr = w1 + y * 64;
        float h0 = b1[y], h1 = 0.f, h2 = 0.f, h3 = 0.f; // 4 chains: 16-deep each
#pragma unroll
        for (int x = 0; x < 64; x += 4) {
            h0 = fmaf(wr[x],     p[x],     h0);
            h1 = fmaf(wr[x + 1], p[x + 1], h1);
            h2 = fmaf(wr[x + 2], p[x + 2], h2);
            h3 = fmaf(wr[x + 3], p[x + 3], h3);
        }
        const float h = fmaxf((h0 + h1) + (h2 + h3), 0.f);
#pragma unroll
        for (int c = 0; c < C; ++c) delta[c] = fmaf(w2[c * HID + y], h, delta[c]);
    }

    const int gx = x0 + lx - 1, gy = y0 + ly - 1, gz = z0 + lz - 1;
    const size_t vofs = (size_t)gz * (G * G) + (size_t)gy * G + gx;
    const float ru = rand_u[(size_t)n * G3 + vofs];
    const float m = (ru < 0.5f) ? 1.f : 0.f;

    float* ob = out + (size_t)n * C * G3;
#pragma unroll
    for (int c = 0; c < C; ++c) {
        const float s0 = tile[c][lz][ly][lx];
        ob[(size_t)c * G3 + vofs] = fmaf(delta[c], m, s0);
    }
    premask[(size_t)n * G3 + vofs] = (amax > 0.1f) ? 1.f : 0.f;
}

// ---------------------------------------------------------------------------
// Pass 2a: post-alive pooling on the NEW alpha (read-only on d_out),
// combine with pre-alive mask in-place in d_ws. No cross-thread hazards.
// ---------------------------------------------------------------------------
__global__ __launch_bounds__(256)
void nca_postmask(const float* __restrict__ newstate, float* __restrict__ mask)
{
    const int idx = blockIdx.x * 256 + threadIdx.x; // over NBATCH*G3
    const int n = idx >> 18;
    const int v = idx & (G3 - 1);
    const int x = v & 63, y = (v >> 6) & 63, z = v >> 12;
    const float* ab = newstate + ((size_t)n * C + 3) * G3;
    float mx = -3.0e38f;
#pragma unroll
    for (int dz = -1; dz <= 1; ++dz) {
        const int zz = min(max(z + dz, 0), G - 1);
#pragma unroll
        for (int dy = -1; dy <= 1; ++dy) {
            const int yy = min(max(y + dy, 0), G - 1);
            const int xm = max(x - 1, 0), xp = min(x + 1, G - 1);
            const float* row = ab + (size_t)zz * (G * G) + (size_t)yy * G;
            mx = fmaxf(mx, fmaxf(fmaxf(row[xm], row[x]), row[xp]));
        }
    }
    const float post = (mx > 0.1f) ? 1.f : 0.f;
    mask[idx] *= post;
}

// ---------------------------------------------------------------------------
// Pass 2b: out *= mask (broadcast over channels), float4-vectorized.
// ---------------------------------------------------------------------------
__global__ __launch_bounds__(256)
void nca_apply(float4* __restrict__ out4, const float4* __restrict__ mask4)
{
    const int idx = blockIdx.x * 256 + threadIdx.x; // over NBATCH*C*G3/4
    const size_t base = (size_t)idx * 4;
    const int n = (int)(base >> 22);          // C*G3 = 2^22
    const int v = (int)(base & (G3 - 1));     // G3 = 2^18
    const float4 m = mask4[((size_t)n * G3 + v) >> 2];
    float4 o = out4[idx];
    o.x *= m.x; o.y *= m.y; o.z *= m.z; o.w *= m.w;
    out4[idx] = o;
}

extern "C" void kernel_launch(void* const* d_in, const int* in_sizes, int n_in,
                              void* d_out, int out_size, void* d_ws, size_t ws_size,
                              hipStream_t stream)
{
    const float* state  = (const float*)d_in[0];
    const float* rand_u = (const float*)d_in[1];
    const float* w1     = (const float*)d_in[2];
    const float* b1     = (const float*)d_in[3];
    const float* w2     = (const float*)d_in[4];
    float* out  = (float*)d_out;
    float* mask = (float*)d_ws; // NBATCH*G3 floats = 4 MiB scratch

    nca_update  <<<NBATCH * 8 * 8 * 8, 512, 0, stream>>>(state, rand_u, w1, b1, w2, out, mask);
    nca_postmask<<<(NBATCH * G3) / 256, 256, 0, stream>>>(out, mask);
    nca_apply   <<<(NBATCH * C * G3 / 4) / 256, 256, 0, stream>>>((float4*)out, (const float4*)mask);
}

// Round 2
// 549.156 us; speedup vs baseline: 1.5336x; 1.4453x over previous
//
#include <hip/hip_runtime.h>

constexpr int G = 64;
constexpr int C = 16;
constexpr int NBATCH = 4;
constexpr int HID = 96;
constexpr int G3 = G * G * G; // 262144 = 2^18

// ---------------------------------------------------------------------------
// Pass 1: perception (edge-padded sobel stencil) + fused MLP + stochastic
// update.
//
// R2 change: per-channel double-buffered LDS staging (2 x 4 KB instead of a
// 64 KB 16-channel tile). The 64 KB tile capped residency at 1 block/CU
// (8 waves = 24% occupancy) which left the SIMDs idle 74% of the time
// (VALUBusy 26%). The full tile is unnecessary: the stencil consumes one
// channel at a time, and the center value needed for the output is exactly
// the identity feature p[c]. Halo-load source offsets are precomputed once
// (removes per-load div/mod), and channel c+1's global loads are issued
// before channel c's stencil compute so HBM latency hides under VALU work.
// One 8x8x8 voxel tile per block, 512 threads, 1 voxel/thread.
// ---------------------------------------------------------------------------
__global__ __launch_bounds__(512, 4)
void nca_update(const float* __restrict__ state, const float* __restrict__ rand_u,
                const float* __restrict__ w1, const float* __restrict__ b1,
                const float* __restrict__ w2,
                float* __restrict__ out, float* __restrict__ premask)
{
    // Two channel buffers; 1000 live floats each, padded to 1024 so the
    // second cooperative store (tid+512 in [512,1023]) can land in pad
    // without a branch. 8192 B total -> occupancy is VGPR-limited.
    __shared__ float tile[2][1024];

    const int tid = threadIdx.x;
    const int bid = blockIdx.x;
    const int bx = bid & 7, by = (bid >> 3) & 7, bz = (bid >> 6) & 7, n = bid >> 9;
    const int x0 = bx * 8, y0 = by * 8, z0 = bz * 8;
    const float* sb = state + (size_t)n * C * G3;

    // Precompute the two halo source offsets (identical for every channel).
    // Element i of the 10^3 halo lives at linear LDS index i; source is the
    // edge-clamped global voxel.
    const int i0 = tid;
    const int i1 = min(tid + 512, 999); // tids 488..511 re-read elem 999 (pad write)
    int vo0, vo1;
    {
        int lx = i0 % 10, t = i0 / 10;
        int ly = t % 10, lz = t / 10;
        int gx = min(max(x0 + lx - 1, 0), G - 1);
        int gy = min(max(y0 + ly - 1, 0), G - 1);
        int gz = min(max(z0 + lz - 1, 0), G - 1);
        vo0 = gz * (G * G) + gy * G + gx;
    }
    {
        int lx = i1 % 10, t = i1 / 10;
        int ly = t % 10, lz = t / 10;
        int gx = min(max(x0 + lx - 1, 0), G - 1);
        int gy = min(max(y0 + ly - 1, 0), G - 1);
        int gz = min(max(z0 + lz - 1, 0), G - 1);
        vo1 = gz * (G * G) + gy * G + gx;
    }

    // Issue the per-voxel rand load early; consumed only at the end.
    const int lxl = (tid & 7) + 1, lyl = ((tid >> 3) & 7) + 1, lzl = (tid >> 6) + 1;
    const int gx = x0 + lxl - 1, gy = y0 + lyl - 1, gz = z0 + lzl - 1;
    const size_t vofs = (size_t)gz * (G * G) + (size_t)gy * G + gx;
    const float ru = rand_u[(size_t)n * G3 + vofs];

    // Stage channel 0.
    tile[0][i0] = sb[vo0];
    tile[0][tid + 512] = sb[vo1];
    __syncthreads();

    // Linear base of this thread's stencil corner (lz-1, ly-1, lx-1).
    const int cbase = (lzl - 1) * 100 + (lyl - 1) * 10 + (lxl - 1);

    // Perception features, layout matches w1 columns: x = k*16 + c
    // (k: 0=identity, 1=sobel-z, 2=sobel-y, 3=sobel-x).
    float p[64];
    float amax = -3.0e38f; // 3^3 max of old alpha (c==3); clamped-edge == SAME pool

#pragma unroll
    for (int c = 0; c < C; ++c) {
        // Prefetch next channel into registers (HBM latency hides under the
        // stencil compute below).
        float r0 = 0.f, r1 = 0.f;
        if (c + 1 < C) {
            r0 = sb[(size_t)(c + 1) * G3 + vo0];
            r1 = sb[(size_t)(c + 1) * G3 + vo1];
        }

        const float* buf = tile[c & 1];
        float P0 = 0.f, P2 = 0.f, U0 = 0.f, U2 = 0.f, V0 = 0.f, V2 = 0.f;
        float ctr = 0.f, mx = -3.0e38f;
#pragma unroll
        for (int dz = 0; dz < 3; ++dz) {
            const float gzw = (dz == 1) ? 2.f : 1.f;
#pragma unroll
            for (int dy = 0; dy < 3; ++dy) {
                const float gyw = (dy == 1) ? 2.f : 1.f;
                const float* r = buf + cbase + dz * 100 + dy * 10;
                const float a0 = r[0], a1 = r[1], a2 = r[2];
                const float rs = a0 + 2.f * a1 + a2; // g over x
                if (dz == 0) P0 += gyw * rs;
                if (dz == 2) P2 += gyw * rs;
                if (dy == 0) U0 += gzw * rs;
                if (dy == 2) U2 += gzw * rs;
                V0 += gzw * gyw * a0;
                V2 += gzw * gyw * a2;
                if (dz == 1 && dy == 1) ctr = a1;
                if (c == 3) mx = fmaxf(mx, fmaxf(fmaxf(a0, a1), a2));
            }
        }
        if (c == 3) amax = mx;

        p[c]      = ctr;                    // identity (== old center value)
        p[16 + c] = (P0 - P2) * 0.0625f;    // sobel along d(z)
        p[32 + c] = (U0 - U2) * 0.0625f;    // sobel along h(y)
        p[48 + c] = (V0 - V2) * 0.0625f;    // sobel along w(x)

        if (c + 1 < C) {
            float* nb = tile[(c + 1) & 1];
            nb[i0] = r0;
            nb[tid + 512] = r1;
        }
        __syncthreads(); // covers both: nb writes visible, buf reads done
    }

    float delta[C];
#pragma unroll
    for (int c = 0; c < C; ++c) delta[c] = 0.f;

    // Fused MLP: stream hidden units; h never lives past one iteration.
    // All weight reads are wave-uniform scalar loads.
#pragma unroll 2
    for (int y = 0; y < HID; ++y) {
        const float* wr = w1 + y * 64;
        float h0 = b1[y], h1 = 0.f, h2 = 0.f, h3 = 0.f; // 4 chains, 16-deep each
#pragma unroll
        for (int x = 0; x < 64; x += 4) {
            h0 = fmaf(wr[x],     p[x],     h0);
            h1 = fmaf(wr[x + 1], p[x + 1], h1);
            h2 = fmaf(wr[x + 2], p[x + 2], h2);
            h3 = fmaf(wr[x + 3], p[x + 3], h3);
        }
        const float h = fmaxf((h0 + h1) + (h2 + h3), 0.f);
#pragma unroll
        for (int c = 0; c < C; ++c) delta[c] = fmaf(w2[c * HID + y], h, delta[c]);
    }

    const float m = (ru < 0.5f) ? 1.f : 0.f;

    float* ob = out + (size_t)n * C * G3;
#pragma unroll
    for (int c = 0; c < C; ++c) {
        // p[c] is the identity feature == old center value s0.
        ob[(size_t)c * G3 + vofs] = fmaf(delta[c], m, p[c]);
    }
    premask[(size_t)n * G3 + vofs] = (amax > 0.1f) ? 1.f : 0.f;
}

// ---------------------------------------------------------------------------
// Pass 2a: post-alive pooling on the NEW alpha (read-only on d_out),
// combine with pre-alive mask in-place in d_ws. No cross-thread hazards.
// ---------------------------------------------------------------------------
__global__ __launch_bounds__(256)
void nca_postmask(const float* __restrict__ newstate, float* __restrict__ mask)
{
    const int idx = blockIdx.x * 256 + threadIdx.x; // over NBATCH*G3
    const int n = idx >> 18;
    const int v = idx & (G3 - 1);
    const int x = v & 63, y = (v >> 6) & 63, z = v >> 12;
    const float* ab = newstate + ((size_t)n * C + 3) * G3;
    float mx = -3.0e38f;
#pragma unroll
    for (int dz = -1; dz <= 1; ++dz) {
        const int zz = min(max(z + dz, 0), G - 1);
#pragma unroll
        for (int dy = -1; dy <= 1; ++dy) {
            const int yy = min(max(y + dy, 0), G - 1);
            const int xm = max(x - 1, 0), xp = min(x + 1, G - 1);
            const float* row = ab + (size_t)zz * (G * G) + (size_t)yy * G;
            mx = fmaxf(mx, fmaxf(fmaxf(row[xm], row[x]), row[xp]));
        }
    }
    const float post = (mx > 0.1f) ? 1.f : 0.f;
    mask[idx] *= post;
}

// ---------------------------------------------------------------------------
// Pass 2b: out *= mask (broadcast over channels), float4-vectorized.
// ---------------------------------------------------------------------------
__global__ __launch_bounds__(256)
void nca_apply(float4* __restrict__ out4, const float4* __restrict__ mask4)
{
    const int idx = blockIdx.x * 256 + threadIdx.x; // over NBATCH*C*G3/4
    const size_t base = (size_t)idx * 4;
    const int n = (int)(base >> 22);          // C*G3 = 2^22
    const int v = (int)(base & (G3 - 1));     // G3 = 2^18
    const float4 m = mask4[((size_t)n * G3 + v) >> 2];
    float4 o = out4[idx];
    o.x *= m.x; o.y *= m.y; o.z *= m.z; o.w *= m.w;
    out4[idx] = o;
}

extern "C" void kernel_launch(void* const* d_in, const int* in_sizes, int n_in,
                              void* d_out, int out_size, void* d_ws, size_t ws_size,
                              hipStream_t stream)
{
    const float* state  = (const float*)d_in[0];
    const float* rand_u = (const float*)d_in[1];
    const float* w1     = (const float*)d_in[2];
    const float* b1     = (const float*)d_in[3];
    const float* w2     = (const float*)d_in[4];
    float* out  = (float*)d_out;
    float* mask = (float*)d_ws; // NBATCH*G3 floats = 4 MiB scratch

    nca_update  <<<NBATCH * 8 * 8 * 8, 512, 0, stream>>>(state, rand_u, w1, b1, w2, out, mask);
    nca_postmask<<<(NBATCH * G3) / 256, 256, 0, stream>>>(out, mask);
    nca_apply   <<<(NBATCH * C * G3 / 4) / 256, 256, 0, stream>>>((float4*)out, (const float4*)mask);
}